// Round 7
// baseline (424.216 us; speedup 1.0000x reference)
//
#include <hip/hip_runtime.h>

constexpr int kB  = 16;
constexpr int kLM = 1024;
constexpr int kLX = 1024;
constexpr int kD  = 768;

using short8 = __attribute__((ext_vector_type(8))) short;
using f32x4  = __attribute__((ext_vector_type(4))) float;

__device__ __forceinline__ unsigned short f2bf(float f) {
    unsigned u = __float_as_uint(f);
    u = (u + 0x7FFF + ((u >> 16) & 1)) >> 16;   // RNE
    return (unsigned short)u;
}
__device__ __forceinline__ float bf2f(unsigned short h) {
    return __uint_as_float(((unsigned)h) << 16);
}
__device__ __forceinline__ short8 cvt8(float4 lo, float4 hi) {
    union { short8 v; unsigned short u[8]; } o;
    o.u[0] = f2bf(lo.x); o.u[1] = f2bf(lo.y); o.u[2] = f2bf(lo.z); o.u[3] = f2bf(lo.w);
    o.u[4] = f2bf(hi.x); o.u[5] = f2bf(hi.y); o.u[6] = f2bf(hi.z); o.u[7] = f2bf(hi.w);
    return o.v;
}

// ---------------------------------------------------------------------------
// Transpose + convert: xT[b][d][l] = bf16(x[b][l][d])
// ---------------------------------------------------------------------------
__global__ __launch_bounds__(256) void transpose_cvt_kernel(
    const float* __restrict__ x, unsigned short* __restrict__ xT) {
    __shared__ float tile[64][65];
    const int b  = blockIdx.z;
    const int l0 = blockIdx.x * 64;
    const int d0 = blockIdx.y * 64;
    const int t  = threadIdx.x;
    const int tx = t & 15, ty = t >> 4;
    const float* xb = x + ((size_t)b * kLX + l0) * kD + d0;
#pragma unroll
    for (int p = 0; p < 4; ++p) {
        int r = p * 16 + ty;
        float4 v = *(const float4*)(xb + (size_t)r * kD + tx * 4);
        *(float4*)&tile[r][tx * 4] = v;
    }
    __syncthreads();
    unsigned short* xTb = xT + ((size_t)b * kD + d0) * kLX + l0;
#pragma unroll
    for (int p = 0; p < 4; ++p) {
        int dr = p * 16 + ty;
        ushort4 o;
        o.x = f2bf(tile[tx * 4 + 0][dr]);
        o.y = f2bf(tile[tx * 4 + 1][dr]);
        o.z = f2bf(tile[tx * 4 + 2][dr]);
        o.w = f2bf(tile[tx * 4 + 3][dr]);
        *(ushort4*)(xTb + (size_t)dr * kLX + tx * 4) = o;
    }
}

// W (768x768 fp32) -> bf16. 576 blocks x 256 thr x 4 elems.
__global__ __launch_bounds__(256) void cvt_w_kernel(
    const float* __restrict__ in, unsigned short* __restrict__ out) {
    int i = blockIdx.x * 256 + threadIdx.x;
    float4 v = ((const float4*)in)[i];
    ushort4 o;
    o.x = f2bf(v.x); o.y = f2bf(v.y); o.z = f2bf(v.z); o.w = f2bf(v.w);
    ((ushort4*)out)[i] = o;
}

// ---------------------------------------------------------------------------
// Register-direct NT MFMA GEMM — NO LDS, NO BARRIERS in the K-loop.
// C[i][j] = sum_k A[i][k]*B[j][k]. 128x128 tile, 256 thr (2x2 waves),
// 4x4 x (16x16x32) MFMA per wave. Fragments loaded global->VGPR directly:
// lane reads row (frag*16 + l15), k-seg quad*8 — a wave covers 16 rows x 64 B
// contiguous. Double register buffer, prefetch one K-iter ahead; latency is
// hidden by use-site vmcnt + resident waves (no vmcnt(0) barrier drain).
// AFP32: A is fp32, converted to bf16 in registers AT USE TIME (keeps the
// waitcnt at the MFMA, not at the prefetch).
// ---------------------------------------------------------------------------
template <bool AFP32>
__global__ __launch_bounds__(256) void gemm_nt_reg(
    const void* __restrict__ Av, const unsigned short* __restrict__ B,
    unsigned short* __restrict__ C, int M, int N, int K,
    long sA, long sB, long sC) {
    const int b  = blockIdx.z;
    const int i0 = blockIdx.x * 128;
    const int j0 = blockIdx.y * 128;
    const int t    = threadIdx.x;
    const int wave = t >> 6, lane = t & 63;
    const int wr = (wave >> 1) * 64, wc = (wave & 1) * 64;
    const int quad = lane >> 4, l15 = lane & 15;

    const unsigned short* Ah = AFP32 ? nullptr
        : (const unsigned short*)Av + (size_t)b * sA + (size_t)(i0 + wr + l15) * K + quad * 8;
    const float* Af = AFP32
        ? (const float*)Av + (size_t)b * sA + (size_t)(i0 + wr + l15) * K + quad * 8 : nullptr;
    const unsigned short* Bh =
        B + (size_t)b * sB + (size_t)(j0 + wc + l15) * K + quad * 8;

    f32x4 acc[4][4];
    const f32x4 z = {0.f, 0.f, 0.f, 0.f};
#pragma unroll
    for (int i = 0; i < 4; ++i)
#pragma unroll
        for (int j = 0; j < 4; ++j) acc[i][j] = z;

    short8 ah0[4], ah1[4], bg0[4], bg1[4];
    float4 af0[4][2], af1[4][2];

    auto loadA0 = [&](int k) {
#pragma unroll
        for (int i = 0; i < 4; ++i) {
            if constexpr (AFP32) {
                af0[i][0] = *(const float4*)(Af + (size_t)i * 16 * K + k);
                af0[i][1] = *(const float4*)(Af + (size_t)i * 16 * K + k + 4);
            } else {
                ah0[i] = *(const short8*)(Ah + (size_t)i * 16 * K + k);
            }
        }
    };
    auto loadA1 = [&](int k) {
#pragma unroll
        for (int i = 0; i < 4; ++i) {
            if constexpr (AFP32) {
                af1[i][0] = *(const float4*)(Af + (size_t)i * 16 * K + k);
                af1[i][1] = *(const float4*)(Af + (size_t)i * 16 * K + k + 4);
            } else {
                ah1[i] = *(const short8*)(Ah + (size_t)i * 16 * K + k);
            }
        }
    };
    auto loadB0 = [&](int k) {
#pragma unroll
        for (int j = 0; j < 4; ++j) bg0[j] = *(const short8*)(Bh + (size_t)j * 16 * K + k);
    };
    auto loadB1 = [&](int k) {
#pragma unroll
        for (int j = 0; j < 4; ++j) bg1[j] = *(const short8*)(Bh + (size_t)j * 16 * K + k);
    };
    auto mfma0 = [&]() {
        short8 af[4];
#pragma unroll
        for (int i = 0; i < 4; ++i)
            af[i] = AFP32 ? cvt8(af0[i][0], af0[i][1]) : ah0[i];
#pragma unroll
        for (int i = 0; i < 4; ++i)
#pragma unroll
            for (int j = 0; j < 4; ++j)
                acc[i][j] = __builtin_amdgcn_mfma_f32_16x16x32_bf16(
                    af[i], bg0[j], acc[i][j], 0, 0, 0);
    };
    auto mfma1 = [&]() {
        short8 af[4];
#pragma unroll
        for (int i = 0; i < 4; ++i)
            af[i] = AFP32 ? cvt8(af1[i][0], af1[i][1]) : ah1[i];
#pragma unroll
        for (int i = 0; i < 4; ++i)
#pragma unroll
            for (int j = 0; j < 4; ++j)
                acc[i][j] = __builtin_amdgcn_mfma_f32_16x16x32_bf16(
                    af[i], bg1[j], acc[i][j], 0, 0, 0);
    };

    const int T = K >> 5;          // K/32 tiles; T is even (24 or 32)
    loadA0(0); loadB0(0);
    for (int kt = 0; kt < T; kt += 2) {
        loadA1((kt + 1) << 5);     // prefetch kt+1 (kt+1 <= T-1 since T even)
        loadB1((kt + 1) << 5);
        mfma0();                   // compute kt
        if (kt + 2 < T) {
            loadA0((kt + 2) << 5); // prefetch kt+2
            loadB0((kt + 2) << 5);
        }
        mfma1();                   // compute kt+1
    }

    // C/D layout: col = lane&15, row = quad*4 + reg  [m89/m91 verified]
    unsigned short* Cb = C + (size_t)b * sC + (size_t)(i0 + wr) * N + j0 + wc;
#pragma unroll
    for (int i = 0; i < 4; ++i)
#pragma unroll
        for (int j = 0; j < 4; ++j)
#pragma unroll
            for (int r = 0; r < 4; ++r)
                Cb[(size_t)(i * 16 + quad * 4 + r) * N + j * 16 + l15] =
                    f2bf(acc[i][j][r]);
}

// ---------------------------------------------------------------------------
// Fused beta + pooled. Grid (64,16): 4 blocks/CU. Wave handles 4 rows.
// Cross-wave LDS pre-reduction -> 1 atomicAdd per (s,lane) per block.
// ---------------------------------------------------------------------------
__global__ __launch_bounds__(256) void pool_kernel(
    const float* __restrict__ mainp, const unsigned short* __restrict__ Aout,
    const float* __restrict__ w, float* __restrict__ out) {
    __shared__ float red[4][24][64];   // 24 KB
    const int b     = blockIdx.y;
    const int chunk = blockIdx.x;           // 64 chunks of 16 rows
    const int t     = threadIdx.x;
    const int wave  = t >> 6, lane = t & 63;
    float w1[12], w2[12], ps[12], pm[12];
#pragma unroll
    for (int s = 0; s < 12; ++s) {
        w1[s] = w[s * 64 + lane];
        w2[s] = w[kD + s * 64 + lane];
        ps[s] = 0.f; pm[s] = 0.f;
    }
#pragma unroll
    for (int rr = 0; rr < 4; ++rr) {
        const int row = chunk * 16 + rr * 4 + wave;
        const float* mr = mainp + ((size_t)b * kLM + row) * kD;
        const unsigned short* ar = Aout + ((size_t)b * kLM + row) * kD;
        float sv[12], mv[12], acc = 0.f;
#pragma unroll
        for (int s = 0; s < 12; ++s) {
            float m_ = mr[s * 64 + lane];
            float a_ = bf2f(ar[s * 64 + lane]);
            sv[s] = m_ - a_;
            mv[s] = m_ * a_;
            acc += sv[s] * w1[s] + mv[s] * w2[s];
        }
#pragma unroll
        for (int off = 32; off; off >>= 1) acc += __shfl_xor(acc, off);
#pragma unroll
        for (int s = 0; s < 12; ++s) { ps[s] += acc * sv[s]; pm[s] += acc * mv[s]; }
    }
#pragma unroll
    for (int s = 0; s < 12; ++s) {
        red[wave][s][lane]      = ps[s];
        red[wave][12 + s][lane] = pm[s];
    }
    __syncthreads();
    float* ob = out + (size_t)b * 2 * kD;
    for (int v = t; v < 24 * 64; v += 256) {
        const int sl = v >> 6, ln = v & 63;
        const float sum = red[0][sl][ln] + red[1][sl][ln] +
                          red[2][sl][ln] + red[3][sl][ln];
        const int d = (sl < 12) ? sl * 64 + ln : kD + (sl - 12) * 64 + ln;
        atomicAdd(&ob[d], sum);
    }
}

extern "C" void kernel_launch(void* const* d_in, const int* in_sizes, int n_in,
                              void* d_out, int out_size, void* d_ws, size_t ws_size,
                              hipStream_t stream) {
    const float* mainp = (const float*)d_in[0];  // (B, LM, D)
    const float* x     = (const float*)d_in[1];  // (B, LX, D)
    const float* W     = (const float*)d_in[2];  // (D, D)
    const float* w     = (const float*)d_in[3];  // (2D, 1)
    float* out = (float*)d_out;                  // (B, 2D)

    char* p = (char*)d_ws;
    unsigned short* xT = (unsigned short*)p; p += (size_t)kB * kD * kLX * 2;
    unsigned short* Wb = (unsigned short*)p; p += (size_t)kD * kD * 2;
    unsigned short* G  = (unsigned short*)p; p += (size_t)kB * kD * kD * 2;
    unsigned short* Mt = (unsigned short*)p; p += (size_t)kB * kD * kD * 2;
    unsigned short* Ao = (unsigned short*)p; p += (size_t)kB * kLM * kD * 2;

    hipMemsetAsync(out, 0, (size_t)kB * 2 * kD * sizeof(float), stream);

    transpose_cvt_kernel<<<dim3(kLX / 64, kD / 64, kB), 256, 0, stream>>>(x, xT);
    cvt_w_kernel<<<kD * kD / 1024, 256, 0, stream>>>(W, Wb);

    // G[b] = xT[b] @ xT[b]^T
    gemm_nt_reg<false><<<dim3(kD / 128, kD / 128, kB), 256, 0, stream>>>(
        xT, xT, G, kD, kD, kLX, (long)kD * kLX, (long)kD * kLX, (long)kD * kD);
    // Mt[b] = G[b] @ W^T   (B = W row-major is already K-contiguous)
    gemm_nt_reg<false><<<dim3(kD / 128, kD / 128, kB), 256, 0, stream>>>(
        G, Wb, Mt, kD, kD, kD, (long)kD * kD, 0L, (long)kD * kD);
    // A[b] = main[b] @ Mt[b]^T  (A = fp32 main, cvt in registers at use)
    gemm_nt_reg<true><<<dim3(kLM / 128, kD / 128, kB), 256, 0, stream>>>(
        mainp, Mt, Ao, kLM, kD, kD, (long)kLM * kD, (long)kD * kD, (long)kLM * kD);

    pool_kernel<<<dim3(kLM / 16, kB), 256, 0, stream>>>(mainp, Ao, w, out);
}

// Round 9
// 256.178 us; speedup vs baseline: 1.6559x; 1.6559x over previous
//
#include <hip/hip_runtime.h>

constexpr int kB  = 16;
constexpr int kLM = 1024;
constexpr int kLX = 1024;
constexpr int kD  = 768;

using short8 = __attribute__((ext_vector_type(8))) short;
using f32x4  = __attribute__((ext_vector_type(4))) float;

__device__ __forceinline__ unsigned short f2bf(float f) {
    unsigned u = __float_as_uint(f);
    u = (u + 0x7FFF + ((u >> 16) & 1)) >> 16;   // RNE
    return (unsigned short)u;
}
__device__ __forceinline__ float bf2f(unsigned short h) {
    return __uint_as_float(((unsigned)h) << 16);
}

// async 16B global->LDS copy; dst must be wave-uniform base + lane*16.
__device__ __forceinline__ void gl_lds16(const unsigned short* g, unsigned short* l) {
    auto gp = (const __attribute__((address_space(1))) unsigned int*)g;
    auto lp = (__attribute__((address_space(3))) unsigned int*)l;
    __builtin_amdgcn_global_load_lds(gp, lp, 16, 0, 0);
}

// inverse XOR swizzle: LDS chunk index -> global (row, kseg) element offset
__device__ __forceinline__ size_t chunk_off(int c, int K) {
    int sr = c >> 3, s = c & 7;
    int tt = s ^ (sr & 7);
    int r  = sr * 2 + (tt >> 2);
    int q  = tt & 3;
    return (size_t)r * K + q * 8;
}

// ---------------------------------------------------------------------------
// Prep (one dispatch, item-range):
//   [0,3072)      : x transpose+cvt 64x64 tiles -> xT
//   [3072,6144)   : main fp32 -> bf16 (1024 float4 per item)
//   [6144,6288)   : W fp32 -> bf16
//   [6288,6294)   : zero out (pool accumulates atomically later)
// ---------------------------------------------------------------------------
__global__ __launch_bounds__(256) void prep_kernel(
    const float* __restrict__ x, unsigned short* __restrict__ xT,
    const float* __restrict__ mainp, unsigned short* __restrict__ mainb,
    const float* __restrict__ W, unsigned short* __restrict__ Wb,
    float* __restrict__ out) {
    __shared__ float tile[64][65];
    const int item = blockIdx.x;
    const int t = threadIdx.x;
    if (item < 3072) {
        const int b  = item / 192, rem = item % 192;
        const int l0 = (rem / 12) * 64, d0 = (rem % 12) * 64;
        const int tx = t & 15, ty = t >> 4;
        const float* xb = x + ((size_t)b * kLX + l0) * kD + d0;
#pragma unroll
        for (int p = 0; p < 4; ++p) {
            int r = p * 16 + ty;
            float4 v = *(const float4*)(xb + (size_t)r * kD + tx * 4);
            *(float4*)&tile[r][tx * 4] = v;
        }
        __syncthreads();
        unsigned short* xTb = xT + ((size_t)b * kD + d0) * kLX + l0;
#pragma unroll
        for (int p = 0; p < 4; ++p) {
            int dr = p * 16 + ty;
            ushort4 o;
            o.x = f2bf(tile[tx * 4 + 0][dr]);
            o.y = f2bf(tile[tx * 4 + 1][dr]);
            o.z = f2bf(tile[tx * 4 + 2][dr]);
            o.w = f2bf(tile[tx * 4 + 3][dr]);
            *(ushort4*)(xTb + (size_t)dr * kLX + tx * 4) = o;
        }
    } else if (item < 6144) {
        const size_t base = (size_t)(item - 3072) * 1024;
        const float4* src = (const float4*)mainp + base;
        ushort4* dst = (ushort4*)mainb + base;
#pragma unroll
        for (int u = 0; u < 4; ++u) {
            float4 v = src[t + u * 256];
            ushort4 o;
            o.x = f2bf(v.x); o.y = f2bf(v.y); o.z = f2bf(v.z); o.w = f2bf(v.w);
            dst[t + u * 256] = o;
        }
    } else if (item < 6288) {
        const size_t base = (size_t)(item - 6144) * 1024;
        const float4* src = (const float4*)W + base;
        ushort4* dst = (ushort4*)Wb + base;
#pragma unroll
        for (int u = 0; u < 4; ++u) {
            float4 v = src[t + u * 256];
            ushort4 o;
            o.x = f2bf(v.x); o.y = f2bf(v.y); o.z = f2bf(v.z); o.w = f2bf(v.w);
            dst[t + u * 256] = o;
        }
    } else {
        const size_t base = (size_t)(item - 6288) * 1024;
        float4* dst = (float4*)out + base;
        const float4 z4 = {0.f, 0.f, 0.f, 0.f};
#pragma unroll
        for (int u = 0; u < 4; ++u) dst[t + u * 256] = z4;
    }
}

// ---------------------------------------------------------------------------
// NT bf16 MFMA GEMM, 128x64 tile (more blocks -> 4.5-6/CU, grid was the
// occupancy limiter at 128x128). BK=32, 256 thr; wave w owns rows
// [w*32,w*32+32) x all 64 cols: 2x4 x 16x16x32 MFMA. XOR-swizzled LDS
// chunks (conflict-free), double-buffered async global_load_lds.
// NO min-waves clamp (R5's spill lesson). LDS 24 KB.
// ---------------------------------------------------------------------------
__global__ __launch_bounds__(256) void gemm_nt_kernel(
    const unsigned short* __restrict__ A, const unsigned short* __restrict__ B,
    unsigned short* __restrict__ C, int M, int N, int K,
    long sA, long sB, long sC) {
    __shared__ unsigned short Asm[2][128 * 32];   // 8 KB each
    __shared__ unsigned short Bsm[2][64 * 32];    // 4 KB each
    const int b  = blockIdx.z;
    const int i0 = blockIdx.x * 128;
    const int j0 = blockIdx.y * 64;
    const int t    = threadIdx.x;
    const int wave = t >> 6, lane = t & 63;
    const int quad = lane >> 4, l15 = lane & 15;

    const unsigned short* Ab = A + (size_t)b * sA + (size_t)i0 * K;
    const unsigned short* Bb = B + (size_t)b * sB + (size_t)j0 * K;

    const int cA0 = t, cA1 = t + 256, cB = t;    // A: 512 chunks, B: 256 chunks
    const size_t offA0 = chunk_off(cA0, K);
    const size_t offA1 = chunk_off(cA1, K);
    const size_t offB  = chunk_off(cB, K);

    const int sfr  = ((l15 & 1) * 4 + quad) ^ ((l15 >> 1) & 7);
    const int aOff = wave * 1024 + (l15 >> 1) * 64 + sfr * 8;  // wave*32 rows * 32
    const int bOff = (l15 >> 1) * 64 + sfr * 8;

    f32x4 acc[2][4];
    const f32x4 z = {0.f, 0.f, 0.f, 0.f};
#pragma unroll
    for (int i = 0; i < 2; ++i)
#pragma unroll
        for (int j = 0; j < 4; ++j) acc[i][j] = z;

    const int T = K >> 5;
    // prologue: tile 0 -> buf 0
    gl_lds16(Ab + offA0, Asm[0] + cA0 * 8);
    gl_lds16(Ab + offA1, Asm[0] + cA1 * 8);
    gl_lds16(Bb + offB,  Bsm[0] + cB * 8);

    int buf = 0;
    for (int kt = 0; kt < T; ++kt) {
        __syncthreads();   // tile kt staged
        if (kt + 1 < T) {
            const size_t k = (size_t)(kt + 1) << 5;
            gl_lds16(Ab + offA0 + k, Asm[buf ^ 1] + cA0 * 8);
            gl_lds16(Ab + offA1 + k, Asm[buf ^ 1] + cA1 * 8);
            gl_lds16(Bb + offB + k,  Bsm[buf ^ 1] + cB * 8);
        }
        const unsigned short* aP = Asm[buf] + aOff;
        const unsigned short* bP = Bsm[buf] + bOff;
        short8 af[2], bg[4];
#pragma unroll
        for (int i = 0; i < 2; ++i) af[i] = *(const short8*)(aP + i * 512);
#pragma unroll
        for (int j = 0; j < 4; ++j) bg[j] = *(const short8*)(bP + j * 512);
#pragma unroll
        for (int i = 0; i < 2; ++i)
#pragma unroll
            for (int j = 0; j < 4; ++j)
                acc[i][j] = __builtin_amdgcn_mfma_f32_16x16x32_bf16(
                    af[i], bg[j], acc[i][j], 0, 0, 0);
        buf ^= 1;
    }

    // C/D layout: col = lane&15, row = quad*4 + reg  [m89/m91 verified]
    unsigned short* Cb = C + (size_t)b * sC + (size_t)(i0 + wave * 32) * N + j0;
#pragma unroll
    for (int i = 0; i < 2; ++i)
#pragma unroll
        for (int j = 0; j < 4; ++j)
#pragma unroll
            for (int r = 0; r < 4; ++r)
                Cb[(size_t)(i * 16 + quad * 4 + r) * N + j * 16 + l15] =
                    f2bf(acc[i][j][r]);
}

// ---------------------------------------------------------------------------
// Fused beta + pooled. Grid (64,16): 4 blocks/CU. Wave handles 4 rows.
// Cross-wave LDS pre-reduction -> 1 atomicAdd per (s,lane) per block.
// ---------------------------------------------------------------------------
__global__ __launch_bounds__(256) void pool_kernel(
    const float* __restrict__ mainp, const unsigned short* __restrict__ Aout,
    const float* __restrict__ w, float* __restrict__ out) {
    __shared__ float red[4][24][64];   // 24 KB
    const int b     = blockIdx.y;
    const int chunk = blockIdx.x;           // 64 chunks of 16 rows
    const int t     = threadIdx.x;
    const int wave  = t >> 6, lane = t & 63;
    float w1[12], w2[12], ps[12], pm[12];
#pragma unroll
    for (int s = 0; s < 12; ++s) {
        w1[s] = w[s * 64 + lane];
        w2[s] = w[kD + s * 64 + lane];
        ps[s] = 0.f; pm[s] = 0.f;
    }
#pragma unroll
    for (int rr = 0; rr < 4; ++rr) {
        const int row = chunk * 16 + rr * 4 + wave;
        const float* mr = mainp + ((size_t)b * kLM + row) * kD;
        const unsigned short* ar = Aout + ((size_t)b * kLM + row) * kD;
        float sv[12], mv[12], acc = 0.f;
#pragma unroll
        for (int s = 0; s < 12; ++s) {
            float m_ = mr[s * 64 + lane];
            float a_ = bf2f(ar[s * 64 + lane]);
            sv[s] = m_ - a_;
            mv[s] = m_ * a_;
            acc += sv[s] * w1[s] + mv[s] * w2[s];
        }
#pragma unroll
        for (int off = 32; off; off >>= 1) acc += __shfl_xor(acc, off);
#pragma unroll
        for (int s = 0; s < 12; ++s) { ps[s] += acc * sv[s]; pm[s] += acc * mv[s]; }
    }
#pragma unroll
    for (int s = 0; s < 12; ++s) {
        red[wave][s][lane]      = ps[s];
        red[wave][12 + s][lane] = pm[s];
    }
    __syncthreads();
    float* ob = out + (size_t)b * 2 * kD;
    for (int v = t; v < 24 * 64; v += 256) {
        const int sl = v >> 6, ln = v & 63;
        const float sum = red[0][sl][ln] + red[1][sl][ln] +
                          red[2][sl][ln] + red[3][sl][ln];
        const int d = (sl < 12) ? sl * 64 + ln : kD + (sl - 12) * 64 + ln;
        atomicAdd(&ob[d], sum);
    }
}

extern "C" void kernel_launch(void* const* d_in, const int* in_sizes, int n_in,
                              void* d_out, int out_size, void* d_ws, size_t ws_size,
                              hipStream_t stream) {
    const float* mainp = (const float*)d_in[0];  // (B, LM, D)
    const float* x     = (const float*)d_in[1];  // (B, LX, D)
    const float* W     = (const float*)d_in[2];  // (D, D)
    const float* w     = (const float*)d_in[3];  // (2D, 1)
    float* out = (float*)d_out;                  // (B, 2D)

    char* p = (char*)d_ws;
    unsigned short* xT    = (unsigned short*)p; p += (size_t)kB * kD * kLX * 2;
    unsigned short* mainb = (unsigned short*)p; p += (size_t)kB * kLM * kD * 2;
    unsigned short* Wb    = (unsigned short*)p; p += (size_t)kD * kD * 2;
    unsigned short* G     = (unsigned short*)p; p += (size_t)kB * kD * kD * 2;
    unsigned short* Mt    = (unsigned short*)p; p += (size_t)kB * kD * kD * 2;
    unsigned short* Ao    = (unsigned short*)p; p += (size_t)kB * kLM * kD * 2;

    // prep: transpose+cvt x, cvt main, cvt W, zero out — one dispatch
    prep_kernel<<<6294, 256, 0, stream>>>(x, xT, mainp, mainb, W, Wb, out);

    // G[b] = xT[b] @ xT[b]^T     grid 6x12x16 = 1152 blocks
    gemm_nt_kernel<<<dim3(kD / 128, kD / 64, kB), 256, 0, stream>>>(
        xT, xT, G, kD, kD, kLX, (long)kD * kLX, (long)kD * kLX, (long)kD * kD);
    // Mt[b] = G[b] @ W^T         grid 1152 blocks
    gemm_nt_kernel<<<dim3(kD / 128, kD / 64, kB), 256, 0, stream>>>(
        G, Wb, Mt, kD, kD, kD, (long)kD * kD, 0L, (long)kD * kD);
    // Ao[b] = mainb[b] @ Mt[b]^T grid 8x12x16 = 1536 blocks
    gemm_nt_kernel<<<dim3(kLM / 128, kD / 64, kB), 256, 0, stream>>>(
        mainb, Mt, Ao, kLM, kD, kD, (long)kLM * kD, (long)kD * kD, (long)kLM * kD);

    pool_kernel<<<dim3(kLM / 16, kB), 256, 0, stream>>>(mainp, Ao, w, out);
}